// Round 11
// baseline (470.865 us; speedup 1.0000x reference)
//
#include <hip/hip_runtime.h>
#include <hip/hip_bf16.h>

// Problem constants
#define BD   256
#define SD   512
#define HD   768
#define IMGD 2048
#define TWOH 1536
constexpr float EPSV  = 1e-5f;
constexpr float SCALE = 0.036084391824351615f;  // 1/sqrt(768)
constexpr int   SPLIT = 4;
constexpr int   SBLK  = SD / SPLIT;             // 128 rows per slice
#define GRIDN 1024u  // persistent grid: 4 blocks/CU via launch_bounds(256,4)
#define NSUB  32u    // arrive sub-counters (128B apart -> distinct lines)

typedef __attribute__((ext_vector_type(8))) short short8;
typedef __attribute__((ext_vector_type(4))) float f32x4;

__device__ __forceinline__ short f2bs(float x) {
    __hip_bfloat16 h = __float2bfloat16(x);
    return __builtin_bit_cast(short, h);
}
__device__ __forceinline__ float4 f4sum(float4 a, float4 b) {
    return make_float4(a.x + b.x, a.y + b.y, a.z + b.z, a.w + b.w);
}
__device__ __forceinline__ float4 f4fma(float s, float4 v, float4 acc) {
    return make_float4(fmaf(s, v.x, acc.x), fmaf(s, v.y, acc.y),
                       fmaf(s, v.z, acc.z), fmaf(s, v.w, acc.w));
}

struct GemmSmem {
    __hip_bfloat16 As[2][64][40];
    __hip_bfloat16 Bs[2][64][40];
};

// ---------------------------------------------------------------------------
// Low-contention grid barrier. R10's 530us lesson: 512 pollers on the SAME
// line as 512 atomicAdds bounces the line cross-XCD and starves the adds
// (~70us/barrier, GPU idle: VALUBusy 2.96%). Fix: arrive on NSUB padded
// sub-counters (32 adds/line, lines independent); block 0 alone sums them
// and publishes a SEPARATE release flag; everyone else polls the read-only
// flag line. cnt region must be 0 at kernel start (hipMemsetAsync on-stream,
// replayed by graph). Watchdog (~50ms) converts any residual hang into a
// wrong-answer instead of a 600s timeout; proven benign in R10.
// ---------------------------------------------------------------------------
__device__ __forceinline__ void gbar(unsigned* bar, unsigned round) {
    __syncthreads();
    if (threadIdx.x == 0) {
        __threadfence();                                   // release
        atomicAdd(&bar[(blockIdx.x & (NSUB - 1u)) << 5], 1u);
        unsigned* flag = bar + NSUB * 32u;
        unsigned long long t0 = __builtin_amdgcn_s_memrealtime();
        if (blockIdx.x == 0) {
            const unsigned target = round * GRIDN;
            for (;;) {
                unsigned s = 0;
                #pragma unroll
                for (unsigned i = 0; i < NSUB; ++i)
                    s += __hip_atomic_load(&bar[i << 5], __ATOMIC_RELAXED,
                                           __HIP_MEMORY_SCOPE_AGENT);
                if (s >= target) break;
                __builtin_amdgcn_s_sleep(16);
                if (__builtin_amdgcn_s_memrealtime() - t0 > 5000000ull) break;
            }
            __hip_atomic_store(flag, round, __ATOMIC_RELEASE,
                               __HIP_MEMORY_SCOPE_AGENT);
        } else {
            while (__hip_atomic_load(flag, __ATOMIC_RELAXED,
                                     __HIP_MEMORY_SCOPE_AGENT) < round) {
                __builtin_amdgcn_s_sleep(16);
                if (__builtin_amdgcn_s_memrealtime() - t0 > 5000000ull) break;
            }
        }
        __threadfence();                                   // acquire
    }
    __syncthreads();
}

// ---------------------------------------------------------------------------
// 64x64-tile GEMM core (verified since r4): BK=32, double LDS buffer,
// depth-2 register prefetch. Lambdas deliver two float4 per thread per tile.
// ---------------------------------------------------------------------------
template<bool TRANSB, class AF, class BF>
__device__ __forceinline__ void gemm_core(GemmSmem& smem, AF aload, BF bload,
        const float* __restrict__ bias, float* __restrict__ C,
        int N, int m0, int n0, int NT) {
    const int tid  = threadIdx.x;
    const int w    = tid >> 6, lane = tid & 63;
    const int wr   = w >> 1,  wc   = w & 1;
    const int rsel = lane & 15, ks = (lane >> 4) * 8;
    const int arow = tid >> 2, akc = (tid & 3) * 8;
    const int bkk  = tid >> 3, bnc = (tid & 7) * 8;

    float4 a0v[2], a1v[2], b0v[2], b1v[2];

    auto issue = [&](int slot, int t) {
        aload(t, a0v[slot], a1v[slot]);
        bload(t, b0v[slot], b1v[slot]);
    };
    auto commit = [&](int buf, int slot) {
        short8 pk;
        pk[0]=f2bs(a0v[slot].x); pk[1]=f2bs(a0v[slot].y);
        pk[2]=f2bs(a0v[slot].z); pk[3]=f2bs(a0v[slot].w);
        pk[4]=f2bs(a1v[slot].x); pk[5]=f2bs(a1v[slot].y);
        pk[6]=f2bs(a1v[slot].z); pk[7]=f2bs(a1v[slot].w);
        *(short8*)&smem.As[buf][arow][akc] = pk;
        if (TRANSB) {
            short8 qk;
            qk[0]=f2bs(b0v[slot].x); qk[1]=f2bs(b0v[slot].y);
            qk[2]=f2bs(b0v[slot].z); qk[3]=f2bs(b0v[slot].w);
            qk[4]=f2bs(b1v[slot].x); qk[5]=f2bs(b1v[slot].y);
            qk[6]=f2bs(b1v[slot].z); qk[7]=f2bs(b1v[slot].w);
            *(short8*)&smem.Bs[buf][arow][akc] = qk;
        } else {
            smem.Bs[buf][bnc + 0][bkk] = __float2bfloat16(b0v[slot].x);
            smem.Bs[buf][bnc + 1][bkk] = __float2bfloat16(b0v[slot].y);
            smem.Bs[buf][bnc + 2][bkk] = __float2bfloat16(b0v[slot].z);
            smem.Bs[buf][bnc + 3][bkk] = __float2bfloat16(b0v[slot].w);
            smem.Bs[buf][bnc + 4][bkk] = __float2bfloat16(b1v[slot].x);
            smem.Bs[buf][bnc + 5][bkk] = __float2bfloat16(b1v[slot].y);
            smem.Bs[buf][bnc + 6][bkk] = __float2bfloat16(b1v[slot].z);
            smem.Bs[buf][bnc + 7][bkk] = __float2bfloat16(b1v[slot].w);
        }
    };

    f32x4 zero = {0.f, 0.f, 0.f, 0.f};
    f32x4 acc[2][2] = {{zero, zero}, {zero, zero}};

    issue(0, 0);
    commit(0, 0);
    if (NT > 1) issue(1, 1);
    __syncthreads();

    for (int t = 0; t < NT; ++t) {
        const int cur = t & 1;
        short8 A0 = *(const short8*)&smem.As[cur][wr * 32 + rsel][ks];
        short8 A1 = *(const short8*)&smem.As[cur][wr * 32 + 16 + rsel][ks];
        short8 B0 = *(const short8*)&smem.Bs[cur][wc * 32 + rsel][ks];
        short8 B1 = *(const short8*)&smem.Bs[cur][wc * 32 + 16 + rsel][ks];
        if (t + 1 < NT) commit(cur ^ 1, (t + 1) & 1);
        if (t + 2 < NT) issue(cur, t + 2);
        acc[0][0] = __builtin_amdgcn_mfma_f32_16x16x32_bf16(A0, B0, acc[0][0], 0, 0, 0);
        acc[0][1] = __builtin_amdgcn_mfma_f32_16x16x32_bf16(A0, B1, acc[0][1], 0, 0, 0);
        acc[1][0] = __builtin_amdgcn_mfma_f32_16x16x32_bf16(A1, B0, acc[1][0], 0, 0, 0);
        acc[1][1] = __builtin_amdgcn_mfma_f32_16x16x32_bf16(A1, B1, acc[1][1], 0, 0, 0);
        __syncthreads();
    }

    // C/D layout: col = lane&15, row = (lane>>4)*4 + reg  [m89-verified]
    const int colb = lane & 15, rowb = (lane >> 4) * 4;
    #pragma unroll
    for (int fm = 0; fm < 2; ++fm)
        #pragma unroll
        for (int fn = 0; fn < 2; ++fn)
            #pragma unroll
            for (int r = 0; r < 4; ++r) {
                int row = m0 + wr * 32 + fm * 16 + rowb + r;
                int col = n0 + wc * 32 + fn * 16 + colb;
                float v = acc[fm][fn][r];
                if (bias) v += bias[col];
                C[(size_t)row * N + col] = v;
            }
}

// ---------------------------------------------------------------------------
// Phase bodies — round-7 kernels verbatim, parameterized by virtual block id.
// ---------------------------------------------------------------------------
__device__ void ph_stage1(GemmSmem& smem, int blk,
        const float* __restrict__ imgf, const float* __restrict__ Wp,
        const float* __restrict__ bp, const float* __restrict__ Wiq,
        const float* __restrict__ Wtk, const float* __restrict__ biq,
        float* __restrict__ Pp, float* __restrict__ Wqkp, float* __restrict__ v1) {
    const int tid = threadIdx.x;
    const int arow = tid >> 2, akc = (tid & 3) * 8;
    const int bkk  = tid >> 3, bnc = (tid & 7) * 8;
    if (blk < 192) {
        const int part = blk / 48, tile = blk % 48;
        const int m0 = (tile / 12) * 64, n0 = (tile % 12) * 64, kbeg = part * 512;
        const float* ap = &imgf[(size_t)(m0 + arow) * IMGD + kbeg + akc];
        const float* bq = &Wp[(size_t)(kbeg + bkk) * HD + n0 + bnc];
        auto al = [&](int t, float4& v0, float4& v1_) {
            const float* p = ap + t * 32;
            v0 = *(const float4*)p; v1_ = *(const float4*)(p + 4);
        };
        auto bl = [&](int t, float4& v0, float4& v1_) {
            const float* p = bq + (size_t)t * 32 * HD;
            v0 = *(const float4*)p; v1_ = *(const float4*)(p + 4);
        };
        gemm_core<false>(smem, al, bl, part == 0 ? bp : nullptr,
                         Pp + (size_t)part * BD * HD, HD, m0, n0, 16);
    } else if (blk < 768) {
        const int b2 = blk - 192, part = b2 / 144, tile = b2 % 144;
        const int m0 = (tile / 12) * 64, n0 = (tile % 12) * 64, kbeg = part * 192;
        const float* ap = &Wiq[(size_t)(m0 + arow) * HD + kbeg + akc];
        const float* bq = &Wtk[(size_t)(n0 + arow) * HD + kbeg + akc];
        auto al = [&](int t, float4& v0, float4& v1_) {
            const float* p = ap + t * 32;
            v0 = *(const float4*)p; v1_ = *(const float4*)(p + 4);
        };
        auto bl = [&](int t, float4& v0, float4& v1_) {
            const float* p = bq + t * 32;
            v0 = *(const float4*)p; v1_ = *(const float4*)(p + 4);
        };
        gemm_core<true>(smem, al, bl, nullptr,
                        Wqkp + (size_t)part * HD * HD, HD, m0, n0, 6);
    } else if (blk < 780) {
        const int b2 = blk - 768;
        const int w = tid >> 6, lane = tid & 63;
        float bq[12];
        #pragma unroll
        for (int c = 0; c < 12; ++c) bq[c] = biq[c * 64 + lane];
        const int d0 = b2 * 64 + w * 16;
        for (int i = 0; i < 16; ++i) {
            const float* row = &Wtk[(size_t)(d0 + i) * HD];
            float p = 0.f;
            #pragma unroll
            for (int c = 0; c < 12; ++c) p = fmaf(row[c * 64 + lane], bq[c], p);
            #pragma unroll
            for (int off = 32; off > 0; off >>= 1) p += __shfl_xor(p, off);
            if (lane == 0) v1[d0 + i] = p;
        }
    }
}

__device__ void ph_stage2(GemmSmem& smem, int blk,
        const float* __restrict__ Pp, const float* __restrict__ Wqkp,
        const float* __restrict__ v1, const float* __restrict__ Wiv,
        const float* __restrict__ biv, float* __restrict__ qtp,
        float* __restrict__ ivp) {
    const int tid = threadIdx.x;
    const int arow = tid >> 2, akc = (tid & 3) * 8;
    const int bkk  = tid >> 3, bnc = (tid & 7) * 8;
    const bool isqt = blk < 192;
    const int b2 = isqt ? blk : blk - 192;
    const int part = b2 / 48, tile = b2 % 48;
    const int m0 = (tile / 12) * 64, n0 = (tile % 12) * 64, kbeg = part * 192;

    const float* ap = &Pp[(size_t)(m0 + arow) * HD + kbeg + akc];
    auto al = [&](int t, float4& v0, float4& v1_) {
        const float* p = ap + t * 32;
        float4 x0 = *(const float4*)p, x1 = *(const float4*)(p + 4);
        #pragma unroll
        for (int q = 1; q < 4; ++q) {
            const float* r = p + (size_t)q * BD * HD;
            x0 = f4sum(x0, *(const float4*)r);
            x1 = f4sum(x1, *(const float4*)(r + 4));
        }
        v0 = x0; v1_ = x1;
    };
    if (isqt) {
        const float* bq = &Wqkp[(size_t)(kbeg + bkk) * HD + n0 + bnc];
        auto bl = [&](int t, float4& v0, float4& v1_) {
            const float* p = bq + (size_t)t * 32 * HD;
            float4 x0 = *(const float4*)p, x1 = *(const float4*)(p + 4);
            #pragma unroll
            for (int q = 1; q < 4; ++q) {
                const float* r = p + (size_t)q * HD * HD;
                x0 = f4sum(x0, *(const float4*)r);
                x1 = f4sum(x1, *(const float4*)(r + 4));
            }
            v0 = x0; v1_ = x1;
        };
        gemm_core<false>(smem, al, bl, part == 0 ? v1 : nullptr,
                         qtp + (size_t)part * BD * HD, HD, m0, n0, 6);
    } else {
        const float* bq = &Wiv[(size_t)(kbeg + bkk) * HD + n0 + bnc];
        auto bl = [&](int t, float4& v0, float4& v1_) {
            const float* p = bq + (size_t)t * 32 * HD;
            v0 = *(const float4*)p; v1_ = *(const float4*)(p + 4);
        };
        gemm_core<false>(smem, al, bl, part == 0 ? biv : nullptr,
                         ivp + (size_t)part * BD * HD, HD, m0, n0, 6);
    }
}

__device__ void ph_attn(float (*sacc)[HD], float* sm_, float* sl_, int item,
        const float* __restrict__ tf, const float* __restrict__ qtp,
        float* __restrict__ pacc, float* __restrict__ ml) {
    const int tid = threadIdx.x, w = tid >> 6, lane = tid & 63;
    const int b = item >> 2, sl = item & 3;

    float q[12];
    {
        const float* qp = &qtp[b * HD];
        #pragma unroll
        for (int c = 0; c < 3; ++c) {
            float4 v = *(const float4*)&qp[c * 256 + 4 * lane];
            #pragma unroll
            for (int p = 1; p < 4; ++p)
                v = f4sum(v, *(const float4*)&qp[(size_t)p * BD * HD + c * 256 + 4 * lane]);
            q[c*4+0] = v.x; q[c*4+1] = v.y; q[c*4+2] = v.z; q[c*4+3] = v.w;
        }
    }
    float a[12];
    #pragma unroll
    for (int j = 0; j < 12; ++j) a[j] = 0.f;
    float m = -INFINITY, l = 0.f;

    const int r0 = sl * SBLK + w * (SBLK / 4);
    const float* base = &tf[((size_t)b * SD + r0) * HD];

    float tA[12], tB[12];
    auto loadrow = [&](int i, float* t) {
        const float* row = base + (size_t)i * HD;
        #pragma unroll
        for (int c = 0; c < 3; ++c) {
            float4 v = *(const float4*)&row[c * 256 + 4 * lane];
            t[c*4+0] = v.x; t[c*4+1] = v.y; t[c*4+2] = v.z; t[c*4+3] = v.w;
        }
    };
    auto process = [&](const float* t) {
        float p = 0.f;
        #pragma unroll
        for (int j = 0; j < 12; ++j) p = fmaf(t[j], q[j], p);
        #pragma unroll
        for (int off = 32; off > 0; off >>= 1) p += __shfl_xor(p, off);
        float score = p * SCALE;
        float mn = fmaxf(m, score);
        float eo = __expf(m - mn);
        float en = __expf(score - mn);
        l = fmaf(l, eo, en);
        #pragma unroll
        for (int j = 0; j < 12; ++j) a[j] = fmaf(a[j], eo, en * t[j]);
        m = mn;
    };

    loadrow(0, tA);
    for (int i = 0; i < 32; i += 2) {
        loadrow(i + 1, tB);
        process(tA);
        if (i + 2 < 32) loadrow(i + 2, tA);
        process(tB);
    }

    #pragma unroll
    for (int c = 0; c < 3; ++c)
        #pragma unroll
        for (int j = 0; j < 4; ++j)
            sacc[w][c * 256 + 4 * lane + j] = a[c * 4 + j];
    if (lane == 0) { sm_[w] = m; sl_[w] = l; }
    __syncthreads();
    float gm = fmaxf(fmaxf(sm_[0], sm_[1]), fmaxf(sm_[2], sm_[3]));
    float f0 = __expf(sm_[0] - gm), f1 = __expf(sm_[1] - gm);
    float f2 = __expf(sm_[2] - gm), f3 = __expf(sm_[3] - gm);
    float gl = f0 * sl_[0] + f1 * sl_[1] + f2 * sl_[2] + f3 * sl_[3];
    float* outp = &pacc[(size_t)item * HD];
    #pragma unroll
    for (int jj = 0; jj < 3; ++jj) {
        int c = jj * 256 + tid;
        outp[c] = f0 * sacc[0][c] + f1 * sacc[1][c] + f2 * sacc[2][c] + f3 * sacc[3][c];
    }
    if (tid == 0) { ml[item * 2] = gm; ml[item * 2 + 1] = gl; }
    __syncthreads();
}

__device__ void ph_ctxv(GemmSmem& smem, float (*wgt)[SPLIT], int blk,
        const float* __restrict__ pacc, const float* __restrict__ ml,
        const float* __restrict__ Wtv, const float* __restrict__ btv,
        float* __restrict__ icpp) {
    const int tid = threadIdx.x;
    const int arow = tid >> 2, akc = (tid & 3) * 8;
    const int bkk  = tid >> 3, bnc = (tid & 7) * 8;
    const int part = blk / 48, tile = blk % 48;
    const int m0 = (tile / 12) * 64, n0 = (tile % 12) * 64, kbeg = part * 192;

    if (tid < 64) {
        const int gr = m0 + tid;
        float mv[SPLIT], lv[SPLIT];
        #pragma unroll
        for (int s = 0; s < SPLIT; ++s) {
            mv[s] = ml[(gr * SPLIT + s) * 2];
            lv[s] = ml[(gr * SPLIT + s) * 2 + 1];
        }
        float mx = fmaxf(fmaxf(mv[0], mv[1]), fmaxf(mv[2], mv[3]));
        float f[SPLIT], gl = 0.f;
        #pragma unroll
        for (int s = 0; s < SPLIT; ++s) { f[s] = __expf(mv[s] - mx); gl += f[s] * lv[s]; }
        float inv = 1.f / gl;
        #pragma unroll
        for (int s = 0; s < SPLIT; ++s) wgt[tid][s] = f[s] * inv;
    }
    __syncthreads();

    const float* ap = &pacc[(size_t)(m0 + arow) * SPLIT * HD + kbeg + akc];
    auto al = [&](int t, float4& v0, float4& v1_) {
        const float* p = ap + t * 32;
        float4 x0 = {0.f, 0.f, 0.f, 0.f}, x1 = {0.f, 0.f, 0.f, 0.f};
        #pragma unroll
        for (int s = 0; s < SPLIT; ++s) {
            float wv = wgt[arow][s];
            const float* r = p + (size_t)s * HD;
            x0 = f4fma(wv, *(const float4*)r, x0);
            x1 = f4fma(wv, *(const float4*)(r + 4), x1);
        }
        v0 = x0; v1_ = x1;
    };
    const float* bq = &Wtv[(size_t)(kbeg + bkk) * HD + n0 + bnc];
    auto bl = [&](int t, float4& v0, float4& v1_) {
        const float* p = bq + (size_t)t * 32 * HD;
        v0 = *(const float4*)p; v1_ = *(const float4*)(p + 4);
    };
    gemm_core<false>(smem, al, bl, part == 0 ? btv : nullptr,
                     icpp + (size_t)part * BD * HD, HD, m0, n0, 6);
}

__device__ void ph_wf(GemmSmem& smem, int blk,
        const float* __restrict__ wtd, const float* __restrict__ Wf,
        const float* __restrict__ Wfb, float* __restrict__ ybp) {
    const int tid = threadIdx.x;
    const int arow = tid >> 2, akc = (tid & 3) * 8;
    const int bkk  = tid >> 3, bnc = (tid & 7) * 8;
    const int part = blk / 48, tile = blk % 48;
    const int m0 = (tile / 12) * 64, n0 = (tile % 12) * 64, kbeg = part * 192;
    const float* ap = &wtd[(size_t)(m0 + arow) * TWOH + kbeg + akc];
    const float* bq = &Wf[(size_t)(kbeg + bkk) * HD + n0 + bnc];
    auto al = [&](int t, float4& v0, float4& v1_) {
        const float* p = ap + t * 32;
        v0 = *(const float4*)p; v1_ = *(const float4*)(p + 4);
    };
    auto bl = [&](int t, float4& v0, float4& v1_) {
        const float* p = bq + (size_t)t * 32 * HD;
        v0 = *(const float4*)p; v1_ = *(const float4*)(p + 4);
    };
    gemm_core<false>(smem, al, bl, part == 0 ? Wfb : nullptr,
                     ybp + (size_t)part * BD * HD, HD, m0, n0, 6);
}

__device__ __forceinline__ float block_sum256(float v, float* red, int w, int lane) {
    #pragma unroll
    for (int off = 32; off > 0; off >>= 1) v += __shfl_xor(v, off);
    __syncthreads();
    if (lane == 0) red[w] = v;
    __syncthreads();
    return red[0] + red[1] + red[2] + red[3];
}

__device__ void ph_fuse(float* red, int b,
        const float* __restrict__ icpp, const float* __restrict__ Pp,
        const float* __restrict__ ivp, const float* __restrict__ tf,
        const float* __restrict__ in_g, const float* __restrict__ in_b,
        const float* __restrict__ tn_g, const float* __restrict__ tn_b,
        const float* __restrict__ Wg, const float* __restrict__ bg,
        float* __restrict__ wtd) {
    const int tid = threadIdx.x;
    const int w = tid >> 6, lane = tid & 63;
    float icv[3], tcv[3];
    #pragma unroll
    for (int j = 0; j < 3; ++j) {
        int c = j * 256 + tid;
        float pv = 0.f, ic = 0.f, iv = 0.f;
        #pragma unroll
        for (int q = 0; q < 4; ++q) {
            pv += Pp[(size_t)q * BD * HD + b * HD + c];
            ic += icpp[(size_t)q * BD * HD + b * HD + c];
            iv += ivp[(size_t)q * BD * HD + b * HD + c];
        }
        icv[j] = ic + pv;
        tcv[j] = iv + tf[(size_t)b * SD * HD + c];
    }
    float s_i  = block_sum256(icv[0] + icv[1] + icv[2], red, w, lane);
    float ss_i = block_sum256(icv[0]*icv[0] + icv[1]*icv[1] + icv[2]*icv[2], red, w, lane);
    float s_t  = block_sum256(tcv[0] + tcv[1] + tcv[2], red, w, lane);
    float ss_t = block_sum256(tcv[0]*tcv[0] + tcv[1]*tcv[1] + tcv[2]*tcv[2], red, w, lane);
    const float invh = 1.f / HD;
    float mu_i = s_i * invh, var_i = ss_i * invh - mu_i * mu_i;
    float mu_t = s_t * invh, var_t = ss_t * invh - mu_t * mu_t;
    float rs_i = rsqrtf(var_i + EPSV), rs_t = rsqrtf(var_t + EPSV);
    float icn[3], tcn[3];
    #pragma unroll
    for (int j = 0; j < 3; ++j) {
        int c = j * 256 + tid;
        icn[j] = (icv[j] - mu_i) * rs_i * in_g[c] + in_b[c];
        tcn[j] = (tcv[j] - mu_t) * rs_t * tn_g[c] + tn_b[c];
    }
    float z0p = 0.f, z1p = 0.f;
    #pragma unroll
    for (int j = 0; j < 3; ++j) {
        int c = j * 256 + tid;
        z0p += tcn[j] * Wg[c * 2 + 0] + icn[j] * Wg[(HD + c) * 2 + 0];
        z1p += tcn[j] * Wg[c * 2 + 1] + icn[j] * Wg[(HD + c) * 2 + 1];
    }
    float z0 = block_sum256(z0p, red, w, lane) + bg[0];
    float z1 = block_sum256(z1p, red, w, lane) + bg[1];
    float mx = fmaxf(z0, z1);
    float e0 = __expf(z0 - mx), e1 = __expf(z1 - mx);
    float inv = 1.f / (e0 + e1);
    float g0 = e0 * inv, g1 = e1 * inv;
    #pragma unroll
    for (int j = 0; j < 3; ++j) {
        int c = j * 256 + tid;
        wtd[(size_t)b * TWOH + c]      = tcn[j] * g0;
        wtd[(size_t)b * TWOH + HD + c] = icn[j] * g1;
    }
}

__device__ void ph_final(float* red, int b,
        const float* __restrict__ ybp, const float* __restrict__ fn_g,
        const float* __restrict__ fn_b, float* __restrict__ out) {
    const int tid = threadIdx.x;
    const int w = tid >> 6, lane = tid & 63;
    float v[3];
    #pragma unroll
    for (int j = 0; j < 3; ++j) {
        int c = j * 256 + tid;
        float x = 0.f;
        #pragma unroll
        for (int q = 0; q < 8; ++q) x += ybp[(size_t)q * BD * HD + b * HD + c];
        v[j] = x;
    }
    float s  = block_sum256(v[0] + v[1] + v[2], red, w, lane);
    float ss = block_sum256(v[0]*v[0] + v[1]*v[1] + v[2]*v[2], red, w, lane);
    const float invh = 1.f / HD;
    float mu = s * invh, var = ss * invh - mu * mu;
    float rs = rsqrtf(var + EPSV);
    #pragma unroll
    for (int j = 0; j < 3; ++j) {
        int c = j * 256 + tid;
        float x = (v[j] - mu) * rs * fn_g[c] + fn_b[c];
        float g = 0.5f * x * (1.f + erff(x * 0.7071067811865476f));
        out[b * HD + c] = g;
    }
}

// ---------------------------------------------------------------------------
// Persistent mega-kernel: 7 phases, 6 flag-released grid barriers.
// 1024 blocks x 256 threads; LDS ~21.5KB (x4 = 88KB/CU); launch_bounds(256,4)
// caps VGPR at 128 (R10 compiled at 64) -> 4 blocks/CU, all 1024 co-resident.
// ---------------------------------------------------------------------------
struct MegaParams {
    const float *tf, *imgf, *Wp, *bp, *Wiv, *biv, *Wiq, *biq, *Wtk, *Wtv, *btv,
                *tn_g, *tn_b, *in_g, *in_b, *Wf, *Wfb, *fn_g, *fn_b, *Wg, *bg;
    float *Pp, *Wqkp, *v1, *qtp, *ivp, *icpp, *ybp, *wtd, *pacc, *ml, *out;
    unsigned* bar;
};

__global__ __launch_bounds__(256, 4) void mega(MegaParams P) {
    __shared__ __align__(16) char arena[sizeof(GemmSmem)];   // 20.5KB
    __shared__ float wgt[64][SPLIT];
    __shared__ float redm[4];
    GemmSmem& smem = *reinterpret_cast<GemmSmem*>(arena);
    float (*sacc)[HD] = reinterpret_cast<float(*)[HD]>(arena);   // 12288B
    float* sm_ = reinterpret_cast<float*>(arena + 12288);
    float* sl_ = reinterpret_cast<float*>(arena + 12304);
    const int blk = blockIdx.x;
    unsigned* bar = P.bar;

    if (blk < 780) ph_stage1(smem, blk, P.imgf, P.Wp, P.bp, P.Wiq, P.Wtk,
                             P.biq, P.Pp, P.Wqkp, P.v1);
    gbar(bar, 1);
    if (blk < 384) ph_stage2(smem, blk, P.Pp, P.Wqkp, P.v1, P.Wiv, P.biv,
                             P.qtp, P.ivp);
    gbar(bar, 2);
    ph_attn(sacc, sm_, sl_, blk, P.tf, P.qtp, P.pacc, P.ml);   // 1024 items
    gbar(bar, 3);
    if (blk < 192) ph_ctxv(smem, wgt, blk, P.pacc, P.ml, P.Wtv, P.btv, P.icpp);
    gbar(bar, 4);
    if (blk < 256) ph_fuse(redm, blk, P.icpp, P.Pp, P.ivp, P.tf, P.in_g, P.in_b,
                           P.tn_g, P.tn_b, P.Wg, P.bg, P.wtd);
    gbar(bar, 5);
    if (blk < 384) ph_wf(smem, blk, P.wtd, P.Wf, P.Wfb, P.ybp);
    gbar(bar, 6);
    if (blk < 256) ph_final(redm, blk, P.ybp, P.fn_g, P.fn_b, P.out);
}

// ---------------------------------------------------------------------------
extern "C" void kernel_launch(void* const* d_in, const int* in_sizes, int n_in,
                              void* d_out, int out_size, void* d_ws, size_t ws_size,
                              hipStream_t stream) {
    const float* tf   = (const float*)d_in[0];
    const float* imgf = (const float*)d_in[1];
    const float* Wp   = (const float*)d_in[2];
    const float* bp   = (const float*)d_in[3];
    // d_in[4..7] (Wtq,btq,Wik,bik): dead — softmax over 1 element == 1 exactly
    const float* Wiv  = (const float*)d_in[8];
    const float* biv  = (const float*)d_in[9];
    const float* Wiq  = (const float*)d_in[10];
    const float* biq  = (const float*)d_in[11];
    const float* Wtk  = (const float*)d_in[12];
    // d_in[13] (btk): per-b constant on scores — softmax-invariant, dropped
    const float* Wtv  = (const float*)d_in[14];
    const float* btv  = (const float*)d_in[15];
    const float* tn_g = (const float*)d_in[16];
    const float* tn_b = (const float*)d_in[17];
    const float* in_g = (const float*)d_in[18];
    const float* in_b = (const float*)d_in[19];
    const float* Wf   = (const float*)d_in[20];
    const float* bff  = (const float*)d_in[21];
    const float* fn_g = (const float*)d_in[22];
    const float* fn_b = (const float*)d_in[23];
    const float* Wg   = (const float*)d_in[24];
    const float* bg   = (const float*)d_in[25];

    float* ws    = (float*)d_ws;
    float* Pp    = ws;                      // 4 * B*H
    float* Wqkp  = Pp    + 4 * BD * HD;     // 4 * H*H
    float* v1    = Wqkp  + 4 * HD * HD;     // H
    float* qtp   = v1    + HD;              // 4 * B*H
    float* ivp   = qtp   + 4 * BD * HD;     // 4 * B*H
    float* icpp  = ivp   + 4 * BD * HD;     // 4 * B*H
    float* ybp   = icpp  + 4 * BD * HD;     // 8 * B*H
    float* wtd   = ybp   + 8 * BD * HD;     // B*2H
    float* pacc  = wtd   + BD * TWOH;       // B*SPLIT*H
    float* ml    = pacc  + (size_t)BD * SPLIT * HD;  // B*SPLIT*2
    unsigned* bar = (unsigned*)(ml + (size_t)BD * SPLIT * 2);  // NSUB*32+32 u32

    MegaParams prm;
    prm.tf = tf; prm.imgf = imgf; prm.Wp = Wp; prm.bp = bp;
    prm.Wiv = Wiv; prm.biv = biv; prm.Wiq = Wiq; prm.biq = biq;
    prm.Wtk = Wtk; prm.Wtv = Wtv; prm.btv = btv;
    prm.tn_g = tn_g; prm.tn_b = tn_b; prm.in_g = in_g; prm.in_b = in_b;
    prm.Wf = Wf; prm.Wfb = bff; prm.fn_g = fn_g; prm.fn_b = fn_b;
    prm.Wg = Wg; prm.bg = bg;
    prm.Pp = Pp; prm.Wqkp = Wqkp; prm.v1 = v1; prm.qtp = qtp; prm.ivp = ivp;
    prm.icpp = icpp; prm.ybp = ybp; prm.wtd = wtd; prm.pacc = pacc; prm.ml = ml;
    prm.out = (float*)d_out;
    prm.bar = bar;

    // Barrier state MUST be 0 at kernel start; async memset is captured into
    // the graph and replays before every launch (verified in R10).
    hipMemsetAsync(bar, 0, (NSUB * 32u + 32u) * sizeof(unsigned), stream);
    mega<<<dim3((int)GRIDN), dim3(256), 0, stream>>>(prm);
}

// Round 12
// 145.540 us; speedup vs baseline: 3.2353x; 3.2353x over previous
//
#include <hip/hip_runtime.h>
#include <hip/hip_bf16.h>

// Problem constants
#define BD   256
#define SD   512
#define HD   768
#define IMGD 2048
#define TWOH 1536
constexpr float EPSV  = 1e-5f;
constexpr float SCALE = 0.036084391824351615f;  // 1/sqrt(768)
constexpr int   SPLIT = 4;
constexpr int   SBLK  = SD / SPLIT;             // 128 rows per slice

typedef __attribute__((ext_vector_type(8))) short short8;
typedef __attribute__((ext_vector_type(4))) float f32x4;

__device__ __forceinline__ short f2bs(float x) {
    __hip_bfloat16 h = __float2bfloat16(x);
    return __builtin_bit_cast(short, h);
}
__device__ __forceinline__ float4 f4sum(float4 a, float4 b) {
    return make_float4(a.x + b.x, a.y + b.y, a.z + b.z, a.w + b.w);
}
__device__ __forceinline__ float4 f4fma(float s, float4 v, float4 acc) {
    return make_float4(fmaf(s, v.x, acc.x), fmaf(s, v.y, acc.y),
                       fmaf(s, v.z, acc.z), fmaf(s, v.w, acc.w));
}

struct GemmSmem {
    __hip_bfloat16 As[2][64][40];  // [buf][m][k] padded rows (80B)
    __hip_bfloat16 Bs[2][64][40];  // [buf][n][k]
};

// ---------------------------------------------------------------------------
// 64x64-tile GEMM core, BK=32, double LDS buffer + depth-2 register prefetch.
// ALoad/BLoad lambdas deliver two float4s per thread per tile (may sum
// split-K partials from producers). TRANSB: B staged as [N,K] rows.
// ---------------------------------------------------------------------------
template<bool TRANSB, class AF, class BF>
__device__ __forceinline__ void gemm_core(GemmSmem& smem, AF aload, BF bload,
        const float* __restrict__ bias, float* __restrict__ C,
        int N, int m0, int n0, int NT) {
    const int tid  = threadIdx.x;
    const int w    = tid >> 6, lane = tid & 63;
    const int wr   = w >> 1,  wc   = w & 1;
    const int rsel = lane & 15, ks = (lane >> 4) * 8;
    const int arow = tid >> 2, akc = (tid & 3) * 8;
    const int bkk  = tid >> 3, bnc = (tid & 7) * 8;

    float4 a0v[2], a1v[2], b0v[2], b1v[2];   // two prefetch slots

    auto issue = [&](int slot, int t) {
        aload(t, a0v[slot], a1v[slot]);
        bload(t, b0v[slot], b1v[slot]);
    };
    auto commit = [&](int buf, int slot) {
        short8 pk;
        pk[0]=f2bs(a0v[slot].x); pk[1]=f2bs(a0v[slot].y);
        pk[2]=f2bs(a0v[slot].z); pk[3]=f2bs(a0v[slot].w);
        pk[4]=f2bs(a1v[slot].x); pk[5]=f2bs(a1v[slot].y);
        pk[6]=f2bs(a1v[slot].z); pk[7]=f2bs(a1v[slot].w);
        *(short8*)&smem.As[buf][arow][akc] = pk;
        if (TRANSB) {
            short8 qk;
            qk[0]=f2bs(b0v[slot].x); qk[1]=f2bs(b0v[slot].y);
            qk[2]=f2bs(b0v[slot].z); qk[3]=f2bs(b0v[slot].w);
            qk[4]=f2bs(b1v[slot].x); qk[5]=f2bs(b1v[slot].y);
            qk[6]=f2bs(b1v[slot].z); qk[7]=f2bs(b1v[slot].w);
            *(short8*)&smem.Bs[buf][arow][akc] = qk;
        } else {
            smem.Bs[buf][bnc + 0][bkk] = __float2bfloat16(b0v[slot].x);
            smem.Bs[buf][bnc + 1][bkk] = __float2bfloat16(b0v[slot].y);
            smem.Bs[buf][bnc + 2][bkk] = __float2bfloat16(b0v[slot].z);
            smem.Bs[buf][bnc + 3][bkk] = __float2bfloat16(b0v[slot].w);
            smem.Bs[buf][bnc + 4][bkk] = __float2bfloat16(b1v[slot].x);
            smem.Bs[buf][bnc + 5][bkk] = __float2bfloat16(b1v[slot].y);
            smem.Bs[buf][bnc + 6][bkk] = __float2bfloat16(b1v[slot].z);
            smem.Bs[buf][bnc + 7][bkk] = __float2bfloat16(b1v[slot].w);
        }
    };

    f32x4 zero = {0.f, 0.f, 0.f, 0.f};
    f32x4 acc[2][2] = {{zero, zero}, {zero, zero}};

    issue(0, 0);
    commit(0, 0);                 // one unavoidable cold vmcnt(0) wait
    if (NT > 1) issue(1, 1);
    __syncthreads();

    for (int t = 0; t < NT; ++t) {
        const int cur = t & 1;
        short8 A0 = *(const short8*)&smem.As[cur][wr * 32 + rsel][ks];
        short8 A1 = *(const short8*)&smem.As[cur][wr * 32 + 16 + rsel][ks];
        short8 B0 = *(const short8*)&smem.Bs[cur][wc * 32 + rsel][ks];
        short8 B1 = *(const short8*)&smem.Bs[cur][wc * 32 + 16 + rsel][ks];
        if (t + 1 < NT) commit(cur ^ 1, (t + 1) & 1);
        if (t + 2 < NT) issue(cur, t + 2);
        acc[0][0] = __builtin_amdgcn_mfma_f32_16x16x32_bf16(A0, B0, acc[0][0], 0, 0, 0);
        acc[0][1] = __builtin_amdgcn_mfma_f32_16x16x32_bf16(A0, B1, acc[0][1], 0, 0, 0);
        acc[1][0] = __builtin_amdgcn_mfma_f32_16x16x32_bf16(A1, B0, acc[1][0], 0, 0, 0);
        acc[1][1] = __builtin_amdgcn_mfma_f32_16x16x32_bf16(A1, B1, acc[1][1], 0, 0, 0);
        __syncthreads();
    }

    // C/D layout: col = lane&15, row = (lane>>4)*4 + reg  [m89-verified]
    const int colb = lane & 15, rowb = (lane >> 4) * 4;
    #pragma unroll
    for (int fm = 0; fm < 2; ++fm)
        #pragma unroll
        for (int fn = 0; fn < 2; ++fn)
            #pragma unroll
            for (int r = 0; r < 4; ++r) {
                int row = m0 + wr * 32 + fm * 16 + rowb + r;
                int col = n0 + wc * 32 + fn * 16 + colb;
                float v = acc[fm][fn][r];
                if (bias) v += bias[col];
                C[(size_t)row * N + col] = v;
            }
}

// ---------------------------------------------------------------------------
// Stage 1:
//  blocks [0,192):   P_p   = imgf @ Wp  split-K x4 (K=512 each) + bp in p=0
//  blocks [192,480): Wqk_p = Wiq @ Wtk^T split-K x2 (K=384 each)
//  blocks [480,492): v1[d] = sum_e biq[e]*Wtk[d,e]
// ---------------------------------------------------------------------------
__global__ __launch_bounds__(256) void stage1(const float* __restrict__ imgf,
                                              const float* __restrict__ Wp,
                                              const float* __restrict__ bp,
                                              const float* __restrict__ Wiq,
                                              const float* __restrict__ Wtk,
                                              const float* __restrict__ biq,
                                              float* __restrict__ Pp,
                                              float* __restrict__ Wqkp,
                                              float* __restrict__ v1) {
    __shared__ GemmSmem smem;
    const int blk = blockIdx.x, tid = threadIdx.x;
    const int arow = tid >> 2, akc = (tid & 3) * 8;
    const int bkk  = tid >> 3, bnc = (tid & 7) * 8;
    if (blk < 192) {
        const int part = blk / 48, tile = blk % 48;
        const int m0 = (tile / 12) * 64, n0 = (tile % 12) * 64, kbeg = part * 512;
        const float* ap = &imgf[(size_t)(m0 + arow) * IMGD + kbeg + akc];
        const float* bq = &Wp[(size_t)(kbeg + bkk) * HD + n0 + bnc];
        auto al = [&](int t, float4& v0, float4& v1_) {
            const float* p = ap + t * 32;
            v0 = *(const float4*)p; v1_ = *(const float4*)(p + 4);
        };
        auto bl = [&](int t, float4& v0, float4& v1_) {
            const float* p = bq + (size_t)t * 32 * HD;
            v0 = *(const float4*)p; v1_ = *(const float4*)(p + 4);
        };
        gemm_core<false>(smem, al, bl, part == 0 ? bp : nullptr,
                         Pp + (size_t)part * BD * HD, HD, m0, n0, 16);
    } else if (blk < 480) {
        const int b2 = blk - 192, part = b2 / 144, tile = b2 % 144;
        const int m0 = (tile / 12) * 64, n0 = (tile % 12) * 64, kbeg = part * 384;
        const float* ap = &Wiq[(size_t)(m0 + arow) * HD + kbeg + akc];
        const float* bq = &Wtk[(size_t)(n0 + arow) * HD + kbeg + akc];
        auto al = [&](int t, float4& v0, float4& v1_) {
            const float* p = ap + t * 32;
            v0 = *(const float4*)p; v1_ = *(const float4*)(p + 4);
        };
        auto bl = [&](int t, float4& v0, float4& v1_) {
            const float* p = bq + t * 32;
            v0 = *(const float4*)p; v1_ = *(const float4*)(p + 4);
        };
        gemm_core<true>(smem, al, bl, nullptr,
                        Wqkp + (size_t)part * HD * HD, HD, m0, n0, 12);
    } else {
        const int b2 = blk - 480;               // 12 blocks x 64 rows
        const int w = tid >> 6, lane = tid & 63;
        float bq[12];
        #pragma unroll
        for (int c = 0; c < 12; ++c) bq[c] = biq[c * 64 + lane];
        const int d0 = b2 * 64 + w * 16;
        for (int i = 0; i < 16; ++i) {
            const float* row = &Wtk[(size_t)(d0 + i) * HD];
            float p = 0.f;
            #pragma unroll
            for (int c = 0; c < 12; ++c) p = fmaf(row[c * 64 + lane], bq[c], p);
            #pragma unroll
            for (int off = 32; off > 0; off >>= 1) p += __shfl_xor(p, off);
            if (lane == 0) v1[d0 + i] = p;
        }
    }
}

// Stage 2: qt_p = (SUM P) @ (SUM Wqk) split-K x2 (+v1 in p=0);
//          iv_p = (SUM P) @ Wiv split-K x2 (+biv in p=0)
__global__ __launch_bounds__(256) void stage2(const float* __restrict__ Pp,
                                              const float* __restrict__ Wqkp,
                                              const float* __restrict__ v1,
                                              const float* __restrict__ Wiv,
                                              const float* __restrict__ biv,
                                              float* __restrict__ qtp,
                                              float* __restrict__ ivp) {
    __shared__ GemmSmem smem;
    const int blk = blockIdx.x, tid = threadIdx.x;
    const int arow = tid >> 2, akc = (tid & 3) * 8;
    const int bkk  = tid >> 3, bnc = (tid & 7) * 8;
    const bool isqt = blk < 96;
    const int b2 = isqt ? blk : blk - 96;
    const int part = b2 / 48, tile = b2 % 48;
    const int m0 = (tile / 12) * 64, n0 = (tile % 12) * 64, kbeg = part * 384;

    const float* ap = &Pp[(size_t)(m0 + arow) * HD + kbeg + akc];
    auto al = [&](int t, float4& v0, float4& v1_) {          // A = sum of 4 P parts
        const float* p = ap + t * 32;
        float4 x0 = *(const float4*)p, x1 = *(const float4*)(p + 4);
        #pragma unroll
        for (int q = 1; q < 4; ++q) {
            const float* r = p + (size_t)q * BD * HD;
            x0 = f4sum(x0, *(const float4*)r);
            x1 = f4sum(x1, *(const float4*)(r + 4));
        }
        v0 = x0; v1_ = x1;
    };
    if (isqt) {
        const float* bq = &Wqkp[(size_t)(kbeg + bkk) * HD + n0 + bnc];
        auto bl = [&](int t, float4& v0, float4& v1_) {      // B = sum of 2 Wqk parts
            const float* p = bq + (size_t)t * 32 * HD;
            v0 = f4sum(*(const float4*)p, *(const float4*)(p + (size_t)HD * HD));
            v1_ = f4sum(*(const float4*)(p + 4), *(const float4*)(p + (size_t)HD * HD + 4));
        };
        gemm_core<false>(smem, al, bl, part == 0 ? v1 : nullptr,
                         qtp + (size_t)part * BD * HD, HD, m0, n0, 12);
    } else {
        const float* bq = &Wiv[(size_t)(kbeg + bkk) * HD + n0 + bnc];
        auto bl = [&](int t, float4& v0, float4& v1_) {
            const float* p = bq + (size_t)t * 32 * HD;
            v0 = *(const float4*)p; v1_ = *(const float4*)(p + 4);
        };
        gemm_core<false>(smem, al, bl, part == 0 ? biv : nullptr,
                         ivp + (size_t)part * BD * HD, HD, m0, n0, 12);
    }
}

// ---------------------------------------------------------------------------
// Streaming flash pass over text_features. Grid = 1024 = B*SPLIT, one item
// per block (4 blocks/CU). Per wave: 32 rows, 2-deep ping-pong prefetch,
// branchless online softmax (fast exp). Partials -> pacc (768-stride) + ml.
// ---------------------------------------------------------------------------
__global__ __launch_bounds__(256) void stream_attn(const float* __restrict__ tf,
                                                   const float* __restrict__ qtp,
                                                   float* __restrict__ pacc,
                                                   float* __restrict__ ml) {
    const int tid = threadIdx.x, w = tid >> 6, lane = tid & 63;
    const int item = blockIdx.x;
    const int b = item >> 2, sl = item & 3;
    __shared__ float sacc[4][HD];
    __shared__ float sm_[4], sl_[4];

    float q[12];
    {
        const float* qp0 = &qtp[b * HD];
        const float* qp1 = qp0 + (size_t)BD * HD;
        #pragma unroll
        for (int c = 0; c < 3; ++c) {
            float4 v = f4sum(*(const float4*)&qp0[c * 256 + 4 * lane],
                             *(const float4*)&qp1[c * 256 + 4 * lane]);
            q[c*4+0] = v.x; q[c*4+1] = v.y; q[c*4+2] = v.z; q[c*4+3] = v.w;
        }
    }
    float a[12];
    #pragma unroll
    for (int j = 0; j < 12; ++j) a[j] = 0.f;
    float m = -INFINITY, l = 0.f;

    const int r0 = sl * SBLK + w * (SBLK / 4);  // 32 rows per wave
    const float* base = &tf[((size_t)b * SD + r0) * HD];

    float tA[12], tB[12];
    auto loadrow = [&](int i, float* t) {
        const float* row = base + (size_t)i * HD;
        #pragma unroll
        for (int c = 0; c < 3; ++c) {
            float4 v = *(const float4*)&row[c * 256 + 4 * lane];
            t[c*4+0] = v.x; t[c*4+1] = v.y; t[c*4+2] = v.z; t[c*4+3] = v.w;
        }
    };
    auto process = [&](const float* t) {
        float p = 0.f;
        #pragma unroll
        for (int j = 0; j < 12; ++j) p = fmaf(t[j], q[j], p);
        #pragma unroll
        for (int off = 32; off > 0; off >>= 1) p += __shfl_xor(p, off);
        float score = p * SCALE;                 // wave-uniform
        float mn = fmaxf(m, score);
        float eo = __expf(m - mn);               // 0 on first row (m=-inf)
        float en = __expf(score - mn);
        l = fmaf(l, eo, en);
        #pragma unroll
        for (int j = 0; j < 12; ++j) a[j] = fmaf(a[j], eo, en * t[j]);
        m = mn;
    };

    loadrow(0, tA);
    for (int i = 0; i < 32; i += 2) {
        loadrow(i + 1, tB);
        process(tA);
        if (i + 2 < 32) loadrow(i + 2, tA);
        process(tB);
    }

    // merge 4 waves
    #pragma unroll
    for (int c = 0; c < 3; ++c)
        #pragma unroll
        for (int j = 0; j < 4; ++j)
            sacc[w][c * 256 + 4 * lane + j] = a[c * 4 + j];
    if (lane == 0) { sm_[w] = m; sl_[w] = l; }
    __syncthreads();
    float gm = fmaxf(fmaxf(sm_[0], sm_[1]), fmaxf(sm_[2], sm_[3]));
    float f0 = __expf(sm_[0] - gm), f1 = __expf(sm_[1] - gm);
    float f2 = __expf(sm_[2] - gm), f3 = __expf(sm_[3] - gm);
    float gl = f0 * sl_[0] + f1 * sl_[1] + f2 * sl_[2] + f3 * sl_[3];
    float* outp = &pacc[(size_t)item * HD];
    #pragma unroll
    for (int jj = 0; jj < 3; ++jj) {
        int c = jj * 256 + tid;
        outp[c] = f0 * sacc[0][c] + f1 * sacc[1][c] + f2 * sacc[2][c] + f3 * sacc[3][c];
    }
    if (tid == 0) { ml[item * 2] = gm; ml[item * 2 + 1] = gl; }
}

// ---------------------------------------------------------------------------
// icp_p = ctx @ Wtv split-K x2 (+btv in p=0), with the SPLIT-partial softmax
// merge fused into the A-load: prologue computes per-row weights into LDS,
// A-lambda does the 4-part weighted sum on the fly (ctx never materialized).
// ---------------------------------------------------------------------------
__global__ __launch_bounds__(256) void gemm_ctxv(const float* __restrict__ pacc,
                                                 const float* __restrict__ ml,
                                                 const float* __restrict__ Wtv,
                                                 const float* __restrict__ btv,
                                                 float* __restrict__ icpp) {
    __shared__ GemmSmem smem;
    __shared__ float wgt[64][SPLIT];
    const int tid = threadIdx.x;
    const int arow = tid >> 2, akc = (tid & 3) * 8;
    const int bkk  = tid >> 3, bnc = (tid & 7) * 8;
    const int part = blockIdx.x / 48, tile = blockIdx.x % 48;
    const int m0 = (tile / 12) * 64, n0 = (tile % 12) * 64, kbeg = part * 384;

    if (tid < 64) {                              // per-row softmax merge weights
        const int gr = m0 + tid;
        float mv[SPLIT], lv[SPLIT];
        #pragma unroll
        for (int s = 0; s < SPLIT; ++s) {
            mv[s] = ml[(gr * SPLIT + s) * 2];
            lv[s] = ml[(gr * SPLIT + s) * 2 + 1];
        }
        float mx = fmaxf(fmaxf(mv[0], mv[1]), fmaxf(mv[2], mv[3]));
        float f[SPLIT], gl = 0.f;
        #pragma unroll
        for (int s = 0; s < SPLIT; ++s) { f[s] = __expf(mv[s] - mx); gl += f[s] * lv[s]; }
        float inv = 1.f / gl;
        #pragma unroll
        for (int s = 0; s < SPLIT; ++s) wgt[tid][s] = f[s] * inv;
    }
    __syncthreads();

    const float* ap = &pacc[(size_t)(m0 + arow) * SPLIT * HD + kbeg + akc];
    auto al = [&](int t, float4& v0, float4& v1_) {
        const float* p = ap + t * 32;
        float4 x0 = {0.f, 0.f, 0.f, 0.f}, x1 = {0.f, 0.f, 0.f, 0.f};
        #pragma unroll
        for (int s = 0; s < SPLIT; ++s) {
            float wv = wgt[arow][s];
            const float* r = p + (size_t)s * HD;
            x0 = f4fma(wv, *(const float4*)r, x0);
            x1 = f4fma(wv, *(const float4*)(r + 4), x1);
        }
        v0 = x0; v1_ = x1;
    };
    const float* bq = &Wtv[(size_t)(kbeg + bkk) * HD + n0 + bnc];
    auto bl = [&](int t, float4& v0, float4& v1_) {
        const float* p = bq + (size_t)t * 32 * HD;
        v0 = *(const float4*)p; v1_ = *(const float4*)(p + 4);
    };
    gemm_core<false>(smem, al, bl, part == 0 ? btv : nullptr,
                     icpp + (size_t)part * BD * HD, HD, m0, n0, 12);
}

// yb_p = wtd @ Wf split-K x4 (+bf in p=0)
__global__ __launch_bounds__(256) void gemm_wf(const float* __restrict__ wtd,
                                               const float* __restrict__ Wf,
                                               const float* __restrict__ bf,
                                               float* __restrict__ ybp) {
    __shared__ GemmSmem smem;
    const int tid = threadIdx.x;
    const int arow = tid >> 2, akc = (tid & 3) * 8;
    const int bkk  = tid >> 3, bnc = (tid & 7) * 8;
    const int part = blockIdx.x / 48, tile = blockIdx.x % 48;
    const int m0 = (tile / 12) * 64, n0 = (tile % 12) * 64, kbeg = part * 384;
    const float* ap = &wtd[(size_t)(m0 + arow) * TWOH + kbeg + akc];
    const float* bq = &Wf[(size_t)(kbeg + bkk) * HD + n0 + bnc];
    auto al = [&](int t, float4& v0, float4& v1_) {
        const float* p = ap + t * 32;
        v0 = *(const float4*)p; v1_ = *(const float4*)(p + 4);
    };
    auto bl = [&](int t, float4& v0, float4& v1_) {
        const float* p = bq + (size_t)t * 32 * HD;
        v0 = *(const float4*)p; v1_ = *(const float4*)(p + 4);
    };
    gemm_core<false>(smem, al, bl, part == 0 ? bf : nullptr,
                     ybp + (size_t)part * BD * HD, HD, m0, n0, 12);
}

__device__ __forceinline__ float block_sum256(float v, float* red, int w, int lane) {
    #pragma unroll
    for (int off = 32; off > 0; off >>= 1) v += __shfl_xor(v, off);
    __syncthreads();
    if (lane == 0) red[w] = v;
    __syncthreads();
    return red[0] + red[1] + red[2] + red[3];
}

// Two LayerNorms + gate softmax + weighted concat -> wtd.
// Sums split-K partials: icp x2, P x4, img_v x2.
__global__ __launch_bounds__(256) void fuse_small(const float* __restrict__ icpp,
                                                  const float* __restrict__ Pp,
                                                  const float* __restrict__ ivp,
                                                  const float* __restrict__ tf,
                                                  const float* __restrict__ in_g,
                                                  const float* __restrict__ in_b,
                                                  const float* __restrict__ tn_g,
                                                  const float* __restrict__ tn_b,
                                                  const float* __restrict__ Wg,
                                                  const float* __restrict__ bg,
                                                  float* __restrict__ wtd) {
    const int b = blockIdx.x, tid = threadIdx.x;
    const int w = tid >> 6, lane = tid & 63;
    __shared__ float red[4];
    float icv[3], tcv[3];
    #pragma unroll
    for (int j = 0; j < 3; ++j) {
        int c = j * 256 + tid;
        float pv = 0.f;
        #pragma unroll
        for (int q = 0; q < 4; ++q) pv += Pp[(size_t)q * BD * HD + b * HD + c];
        float ic = icpp[b * HD + c] + icpp[(size_t)BD * HD + b * HD + c];
        icv[j] = ic + pv;
        float iv = ivp[b * HD + c] + ivp[(size_t)BD * HD + b * HD + c];
        tcv[j] = iv + tf[(size_t)b * SD * HD + c];  // cls = tf[b,0,:]
    }
    float s_i  = block_sum256(icv[0] + icv[1] + icv[2], red, w, lane);
    float ss_i = block_sum256(icv[0]*icv[0] + icv[1]*icv[1] + icv[2]*icv[2], red, w, lane);
    float s_t  = block_sum256(tcv[0] + tcv[1] + tcv[2], red, w, lane);
    float ss_t = block_sum256(tcv[0]*tcv[0] + tcv[1]*tcv[1] + tcv[2]*tcv[2], red, w, lane);
    const float invh = 1.f / HD;
    float mu_i = s_i * invh, var_i = ss_i * invh - mu_i * mu_i;
    float mu_t = s_t * invh, var_t = ss_t * invh - mu_t * mu_t;
    float rs_i = rsqrtf(var_i + EPSV), rs_t = rsqrtf(var_t + EPSV);
    float icn[3], tcn[3];
    #pragma unroll
    for (int j = 0; j < 3; ++j) {
        int c = j * 256 + tid;
        icn[j] = (icv[j] - mu_i) * rs_i * in_g[c] + in_b[c];
        tcn[j] = (tcv[j] - mu_t) * rs_t * tn_g[c] + tn_b[c];
    }
    float z0p = 0.f, z1p = 0.f;
    #pragma unroll
    for (int j = 0; j < 3; ++j) {
        int c = j * 256 + tid;
        z0p += tcn[j] * Wg[c * 2 + 0] + icn[j] * Wg[(HD + c) * 2 + 0];
        z1p += tcn[j] * Wg[c * 2 + 1] + icn[j] * Wg[(HD + c) * 2 + 1];
    }
    float z0 = block_sum256(z0p, red, w, lane) + bg[0];
    float z1 = block_sum256(z1p, red, w, lane) + bg[1];
    float mx = fmaxf(z0, z1);
    float e0 = __expf(z0 - mx), e1 = __expf(z1 - mx);
    float inv = 1.f / (e0 + e1);
    float g0 = e0 * inv, g1 = e1 * inv;
    #pragma unroll
    for (int j = 0; j < 3; ++j) {
        int c = j * 256 + tid;
        wtd[(size_t)b * TWOH + c]      = tcn[j] * g0;
        wtd[(size_t)b * TWOH + HD + c] = icn[j] * g1;
    }
}

// Final LayerNorm + exact gelu -> fp32 out. Sums 4 yb partials.
__global__ __launch_bounds__(256) void final_ln_gelu(const float* __restrict__ ybp,
                                                     const float* __restrict__ fn_g,
                                                     const float* __restrict__ fn_b,
                                                     float* __restrict__ out) {
    const int b = blockIdx.x, tid = threadIdx.x;
    const int w = tid >> 6, lane = tid & 63;
    __shared__ float red[4];
    float v[3];
    #pragma unroll
    for (int j = 0; j < 3; ++j) {
        int c = j * 256 + tid;
        float x = 0.f;
        #pragma unroll
        for (int q = 0; q < 4; ++q) x += ybp[(size_t)q * BD * HD + b * HD + c];
        v[j] = x;
    }
    float s  = block_sum256(v[0] + v[1] + v[2], red, w, lane);
    float ss = block_sum256(v[0]*v[0] + v[1]*v[1] + v[2]*v[2], red, w, lane);
    const float invh = 1.f / HD;
    float mu = s * invh, var = ss * invh - mu * mu;
    float rs = rsqrtf(var + EPSV);
    #pragma unroll
    for (int j = 0; j < 3; ++j) {
        int c = j * 256 + tid;
        float x = (v[j] - mu) * rs * fn_g[c] + fn_b[c];
        float g = 0.5f * x * (1.f + erff(x * 0.7071067811865476f));
        out[b * HD + c] = g;
    }
}

// ---------------------------------------------------------------------------
extern "C" void kernel_launch(void* const* d_in, const int* in_sizes, int n_in,
                              void* d_out, int out_size, void* d_ws, size_t ws_size,
                              hipStream_t stream) {
    const float* tf   = (const float*)d_in[0];
    const float* imgf = (const float*)d_in[1];
    const float* Wp   = (const float*)d_in[2];
    const float* bp   = (const float*)d_in[3];
    // d_in[4..7] (Wtq,btq,Wik,bik): dead — softmax over 1 element == 1 exactly
    const float* Wiv  = (const float*)d_in[8];
    const float* biv  = (const float*)d_in[9];
    const float* Wiq  = (const float*)d_in[10];
    const float* biq  = (const float*)d_in[11];
    const float* Wtk  = (const float*)d_in[12];
    // d_in[13] (btk): per-b constant on scores — softmax-invariant, dropped
    const float* Wtv  = (const float*)d_in[14];
    const float* btv  = (const float*)d_in[15];
    const float* tn_g = (const float*)d_in[16];
    const float* tn_b = (const float*)d_in[17];
    const float* in_g = (const float*)d_in[18];
    const float* in_b = (const float*)d_in[19];
    const float* Wf   = (const float*)d_in[20];
    const float* bff  = (const float*)d_in[21];
    const float* fn_g = (const float*)d_in[22];
    const float* fn_b = (const float*)d_in[23];
    const float* Wg   = (const float*)d_in[24];
    const float* bg   = (const float*)d_in[25];

    float* ws    = (float*)d_ws;
    float* Pp    = ws;                      // 4 * B*H
    float* Wqkp  = Pp    + 4 * BD * HD;     // 2 * H*H
    float* v1    = Wqkp  + 2 * HD * HD;     // H
    float* qtp   = v1    + HD;              // 2 * B*H
    float* ivp   = qtp   + 2 * BD * HD;     // 2 * B*H
    float* icpp  = ivp   + 2 * BD * HD;     // 2 * B*H
    float* ybp   = icpp  + 2 * BD * HD;     // 4 * B*H
    float* wtd   = ybp   + 4 * BD * HD;     // B*2H
    float* pacc  = wtd   + BD * TWOH;       // B*SPLIT*H
    float* ml    = pacc  + (size_t)BD * SPLIT * HD;  // B*SPLIT*2

    stage1<<<492, 256, 0, stream>>>(imgf, Wp, bp, Wiq, Wtk, biq, Pp, Wqkp, v1);
    stage2<<<192, 256, 0, stream>>>(Pp, Wqkp, v1, Wiv, biv, qtp, ivp);
    stream_attn<<<BD * SPLIT, 256, 0, stream>>>(tf, qtp, pacc, ml);
    gemm_ctxv<<<96, 256, 0, stream>>>(pacc, ml, Wtv, btv, icpp);
    fuse_small<<<BD, 256, 0, stream>>>(icpp, Pp, ivp, tf, in_g, in_b, tn_g, tn_b,
                                       Wg, bg, wtd);
    gemm_wf<<<192, 256, 0, stream>>>(wtd, Wf, bff, ybp);
    final_ln_gelu<<<BD, 256, 0, stream>>>(ybp, fn_g, fn_b, (float*)d_out);
}